// Round 3
// baseline (77.414 us; speedup 1.0000x reference)
//
#include <hip/hip_runtime.h>

#define N_WORD 32000
#define DIM    300
#define NJ     75            // float4 per embedding row
#define BQ     32
#define WW     8
#define NNEG   2392
#define PERB   (WW*NNEG)     // 19136 noise samples per b
#define NTOT   (BQ*PERB)     // 612352
#define NGEMB  250           // GEMM blocks (128 v each)
#define NPOSB  8             // positive-term blocks
#define NBLK   (NGEMB+NPOSB)

// ---- kernel 1: tgt bags (blocks 0..31) + zero count table (rest) ----
__global__ __launch_bounds__(256) void prep_kernel(
    const float* __restrict__ char_emb, const float* __restrict__ compo_emb,
    const int* __restrict__ chars, const int* __restrict__ compos,
    float* __restrict__ tgtT, float* __restrict__ tgtN,
    int* __restrict__ count) {
  if (blockIdx.x < BQ) {
    int b = blockIdx.x;
    for (int d = threadIdx.x; d < DIM; d += 256) {
      float a = 0.f;
      #pragma unroll
      for (int j = 0; j < 4; ++j) {
        int c = chars[b*4 + j];
        if (c != 1) a += char_emb[(size_t)c*DIM + d];
      }
      #pragma unroll
      for (int j = 0; j < 8; ++j) {
        int c = compos[b*8 + j];
        if (c != 1) a += compo_emb[(size_t)c*DIM + d];
      }
      tgtT[d*BQ + b] = a;       // [d][b] for GEMM staging
      tgtN[b*DIM + d] = a;      // [b][d] for positive dots
    }
  } else {
    int nb = gridDim.x - BQ;
    int4* c4 = (int4*)count;
    const int tot4 = BQ*N_WORD/4;   // 256000
    for (int i = (blockIdx.x - BQ)*256 + threadIdx.x; i < tot4; i += nb*256)
      c4[i] = make_int4(0, 0, 0, 0);
  }
}

// ---- kernel 2: count[b][v] += 1 over noise (int atomics: deterministic) ----
__global__ __launch_bounds__(256) void hist_kernel(
    const int* __restrict__ noise, int* __restrict__ count) {
  for (int i = blockIdx.x*256 + threadIdx.x; i < NTOT; i += gridDim.x*256) {
    int b = i / PERB;
    atomicAdd(&count[b*N_WORD + noise[i]], 1);
  }
}

// ---- kernel 3: fused GEMM + count-weighted log-sigmoid reduce; pos blocks ----
// GEMM blocks: 128 threads = 2 waves; wave0 dims [0,152), wave1 [152,300).
// lane = vi*4+bh: vi in [0,16) picks v-slot, bh picks 8-b slice. 8 rows/thread
// (v = vbase + r*16 + vi) so each tgt LDS read feeds 32 FMAs.
__global__ __launch_bounds__(128) void s_loss_kernel(
    const float4* __restrict__ w4, const float4* __restrict__ tgtT4,
    const float* __restrict__ tgtN, const float* __restrict__ word,
    const int* __restrict__ ctx, const int* __restrict__ count,
    float* __restrict__ partials) {
  __shared__ float smem[9600];     // tgt tile (38.4 KB), reused as acc buffer
  __shared__ float wred[2];
  int wv = threadIdx.x >> 6, lane = threadIdx.x & 63;

  if (blockIdx.x < NGEMB) {
    float4* tl4 = (float4*)smem;   // [300 dims][8 float4-of-b]
    for (int i = threadIdx.x; i < DIM*8; i += 128) tl4[i] = tgtT4[i];
    __syncthreads();

    int bh = lane & 3, vi = lane >> 2;
    int vbase = blockIdx.x * 128;
    int j0 = wv ? 38 : 0, j1 = wv ? 75 : 38;

    const float4* rp[8];
    #pragma unroll
    for (int r = 0; r < 8; ++r)
      rp[r] = w4 + (size_t)(vbase + r*16 + vi)*NJ + j0;

    float acc[8][8];
    #pragma unroll
    for (int r = 0; r < 8; ++r)
      #pragma unroll
      for (int q = 0; q < 8; ++q) acc[r][q] = 0.f;

    float4 x[8], n[8];
    #pragma unroll
    for (int r = 0; r < 8; ++r) x[r] = rp[r][0];

    for (int j = j0; j < j1; ++j) {
      int jr = j - j0;
      if (j + 1 < j1) {
        #pragma unroll
        for (int r = 0; r < 8; ++r) n[r] = rp[r][jr + 1];  // 1-deep prefetch
      }
      #pragma unroll
      for (int dd = 0; dd < 4; ++dd) {
        float4 t0 = tl4[(j*4 + dd)*8 + bh*2];     // banks 0/8/16/24: no conflict
        float4 t1 = tl4[(j*4 + dd)*8 + bh*2 + 1];
        #pragma unroll
        for (int r = 0; r < 8; ++r) {
          float xd = dd == 0 ? x[r].x : dd == 1 ? x[r].y : dd == 2 ? x[r].z : x[r].w;
          acc[r][0] = fmaf(xd, t0.x, acc[r][0]);
          acc[r][1] = fmaf(xd, t0.y, acc[r][1]);
          acc[r][2] = fmaf(xd, t0.z, acc[r][2]);
          acc[r][3] = fmaf(xd, t0.w, acc[r][3]);
          acc[r][4] = fmaf(xd, t1.x, acc[r][4]);
          acc[r][5] = fmaf(xd, t1.y, acc[r][5]);
          acc[r][6] = fmaf(xd, t1.z, acc[r][6]);
          acc[r][7] = fmaf(xd, t1.w, acc[r][7]);
        }
      }
      #pragma unroll
      for (int r = 0; r < 8; ++r) x[r] = n[r];
    }

    __syncthreads();               // tl4 reads done; safe to overwrite
    // acc buffer layout [wave][v][b], v-stride 33 (pad kills bank conflicts)
    float* ab = smem + wv*4224;
    #pragma unroll
    for (int r = 0; r < 8; ++r) {
      float* dst = ab + (r*16 + vi)*33 + bh*8;
      #pragma unroll
      for (int q = 0; q < 8; ++q) dst[q] = acc[r][q];
    }
    __syncthreads();

    // wave wv reduces b-half [wv*16, wv*16+16) for v = lane, lane+64
    float ls = 0.f;
    #pragma unroll
    for (int k = 0; k < 2; ++k) {
      int v = lane + k*64;
      #pragma unroll
      for (int bb = 0; bb < 16; ++bb) {
        int b = wv*16 + bb;
        float s = smem[v*33 + b] + smem[4224 + v*33 + b];   // full 300-dim dot
        float w = (float)count[(size_t)b*N_WORD + vbase + v];
        ls += w * __logf(1.f/(1.f + __expf(s)) + 1e-32f);
      }
    }
    #pragma unroll
    for (int off = 32; off > 0; off >>= 1) ls += __shfl_down(ls, off);
    if (lane == 0) wred[wv] = ls;
    __syncthreads();
    if (threadIdx.x == 0) partials[blockIdx.x] = wred[0] + wred[1];

  } else {
    // positive terms: 8 blocks x 2 waves; wave handles 16 (b,w) pairs
    int pb = blockIdx.x - NGEMB;
    float ls = 0.f;
    for (int q = 0; q < 16; ++q) {
      int i = pb*32 + wv*16 + q;      // 0..255 = b*8 + w
      int b = i >> 3;
      int c = ctx[i];
      float s = 0.f;
      if (c != 1) {                    // wave-uniform branch
        float p = 0.f;
        #pragma unroll
        for (int t = 0; t < 5; ++t) {
          int d = t*64 + lane;
          if (d < DIM)
            p = fmaf(tgtN[b*DIM + d], word[(size_t)c*DIM + d], p);
        }
        #pragma unroll
        for (int off = 32; off > 0; off >>= 1) p += __shfl_down(p, off);
        s = p;                         // valid on lane 0
      }
      if (lane == 0) ls += __logf(1.f/(1.f + __expf(-s)));
    }
    if (lane == 0) wred[wv] = ls;
    __syncthreads();
    if (threadIdx.x == 0) partials[blockIdx.x] = wred[0] + wred[1];
  }
}

// ---- kernel 4: deterministic final reduction in double ----
__global__ __launch_bounds__(256) void final_kernel(
    const float* __restrict__ partials, float* __restrict__ out) {
  double a = 0.0;
  for (int i = threadIdx.x; i < NBLK; i += 256) a += (double)partials[i];
  #pragma unroll
  for (int off = 32; off > 0; off >>= 1) a += __shfl_down(a, off);
  __shared__ double w2[4];
  int lane = threadIdx.x & 63, wid = threadIdx.x >> 6;
  if (lane == 0) w2[wid] = a;
  __syncthreads();
  if (threadIdx.x == 0)
    out[0] = (float)(-(w2[0] + w2[1] + w2[2] + w2[3]) / (double)BQ);
}

extern "C" void kernel_launch(void* const* d_in, const int* in_sizes, int n_in,
                              void* d_out, int out_size, void* d_ws, size_t ws_size,
                              hipStream_t stream) {
  const float* word_emb  = (const float*)d_in[0];   // [32000,300]
  const float* char_emb  = (const float*)d_in[1];   // [8000,300]
  const float* compo_emb = (const float*)d_in[2];   // [1000,300]
  const int*   chars     = (const int*)d_in[3];     // [32,4]
  const int*   compos    = (const int*)d_in[4];     // [32,8]
  const int*   ctx       = (const int*)d_in[5];     // [32,8]
  const int*   noise     = (const int*)d_in[6];     // [32,8,2392]
  float* out = (float*)d_out;

  float* ws       = (float*)d_ws;
  float* tgtT     = ws;                              // 9600 f  (16B-aligned)
  float* tgtN     = ws + 9600;                       // 9600 f
  int*   count    = (int*)(ws + 19200);              // 1,024,000 ints (4 MB)
  float* partials = ws + 19200 + BQ*N_WORD;          // NBLK floats

  prep_kernel<<<128, 256, 0, stream>>>(char_emb, compo_emb, chars, compos,
                                       tgtT, tgtN, count);
  hist_kernel<<<512, 256, 0, stream>>>(noise, count);
  s_loss_kernel<<<NBLK, 128, 0, stream>>>(
      (const float4*)word_emb, (const float4*)tgtT, tgtN, word_emb,
      ctx, count, partials);
  final_kernel<<<1, 256, 0, stream>>>(partials, out);
}

// Round 4
// 52.381 us; speedup vs baseline: 1.4779x; 1.4779x over previous
//
#include <hip/hip_runtime.h>

#define N_WORD 32000
#define DIM    300
#define KP     320           // K padded to 10 x 32 for MFMA
#define LROW   328           // LDS row stride in bf16 (656 B = 41*16: breaks bank alignment)
#define BQ     32
#define WW     8
#define NNEG   2392
#define PERB   (WW*NNEG)     // 19136
#define NTOT   (BQ*PERB)     // 612352
#define VB     64            // word rows per GEMM block
#define NGEMB  (N_WORD/VB)   // 500
#define NPOSB  8
#define NBLK   (NGEMB+NPOSB)

typedef __attribute__((ext_vector_type(8))) short short8;   // 8 bf16 = 4 VGPR
typedef __attribute__((ext_vector_type(4))) float f32x4;

__device__ __forceinline__ unsigned f2b2(float lo, float hi) {
  // pack two floats to two RNE-rounded bf16 in one u32 (inputs are tame gaussians)
  unsigned ul = __builtin_bit_cast(unsigned, lo);
  unsigned uh = __builtin_bit_cast(unsigned, hi);
  ul = (ul + 0x7FFF + ((ul >> 16) & 1)) >> 16;
  uh = (uh + 0x7FFF + ((uh >> 16) & 1));
  return (ul & 0xFFFFu) | (uh & 0xFFFF0000u);
}
__device__ __forceinline__ unsigned short f2b(float f) {
  unsigned u = __builtin_bit_cast(unsigned, f);
  return (unsigned short)((u + 0x7FFF + ((u >> 16) & 1)) >> 16);
}

// ---- kernel 1: tgt bags (blocks 0..31: f32 + bf16-padded) + zero count ----
__global__ __launch_bounds__(256) void prep_kernel(
    const float* __restrict__ char_emb, const float* __restrict__ compo_emb,
    const int* __restrict__ chars, const int* __restrict__ compos,
    float* __restrict__ tgtN, unsigned short* __restrict__ tgt_bf,
    int* __restrict__ count) {
  if (blockIdx.x < BQ) {
    int b = blockIdx.x;
    for (int d = threadIdx.x; d < KP; d += 256) {
      float a = 0.f;
      if (d < DIM) {
        #pragma unroll
        for (int j = 0; j < 4; ++j) {
          int c = chars[b*4 + j];
          if (c != 1) a += char_emb[(size_t)c*DIM + d];
        }
        #pragma unroll
        for (int j = 0; j < 8; ++j) {
          int c = compos[b*8 + j];
          if (c != 1) a += compo_emb[(size_t)c*DIM + d];
        }
        tgtN[b*DIM + d] = a;
      }
      tgt_bf[b*KP + d] = (d < DIM) ? f2b(a) : (unsigned short)0;
    }
  } else {
    int nb = gridDim.x - BQ;
    int4* c4 = (int4*)count;
    const int tot4 = BQ*N_WORD/4;   // 256000
    for (int i = (blockIdx.x - BQ)*256 + threadIdx.x; i < tot4; i += nb*256)
      c4[i] = make_int4(0, 0, 0, 0);
  }
}

// ---- kernel 2: count[b][v] += 1 over noise (int atomics: deterministic) ----
__global__ __launch_bounds__(256) void hist_kernel(
    const int* __restrict__ noise, int* __restrict__ count) {
  for (int i = blockIdx.x*256 + threadIdx.x; i < NTOT; i += gridDim.x*256) {
    int b = i / PERB;
    atomicAdd(&count[b*N_WORD + noise[i]], 1);
  }
}

// ---- kernel 3: MFMA score GEMM fused with count-weighted log-sigmoid ----
// GEMM blocks: 256 thr = 4 waves; block covers 64 v-rows x all 32 b, K=300.
// Stage: coalesced linear float4 stream of 64 contiguous word rows -> bf16 LDS.
// Wave wv owns v-tile [wv*16, wv*16+16), both b-tiles; 10 k-steps of 32.
__global__ __launch_bounds__(256) void s_loss_kernel(
    const float4* __restrict__ w4, const unsigned* __restrict__ tgtbf2,
    const float* __restrict__ tgtN, const float* __restrict__ word,
    const int* __restrict__ ctx, const int* __restrict__ count,
    float* __restrict__ partials) {
  __shared__ unsigned short wt[VB][LROW];   // 41984 B
  __shared__ unsigned short tt[BQ][LROW];   // 20992 B
  __shared__ float wred[4];
  int tid = threadIdx.x, wv = tid >> 6, lane = tid & 63;

  if (blockIdx.x < NGEMB) {
    int vbase = blockIdx.x * VB;
    // stage word tile: 4800 float4, perfectly coalesced (rows contiguous)
    for (int idx = tid; idx < VB*75; idx += 256) {
      float4 x = w4[(size_t)vbase*75 + idx];
      int row = idx / 75, col = idx - row*75;
      unsigned* dst = (unsigned*)&wt[row][col*4];
      dst[0] = f2b2(x.x, x.y);
      dst[1] = f2b2(x.z, x.w);
    }
    if (tid < VB) {            // zero-pad k in [300,320)
      unsigned* dst = (unsigned*)&wt[tid][300];
      #pragma unroll
      for (int j = 0; j < 10; ++j) dst[j] = 0;
    }
    // stage tgt tile: [32][320] bf16 prepacked (incl. zero pad)
    for (int idx = tid; idx < BQ*(KP/2); idx += 256) {
      int row = idx / (KP/2), kk = idx - row*(KP/2);
      ((unsigned*)&tt[row][0])[kk] = tgtbf2[idx];
    }
    __syncthreads();

    // fragments: same lane->(row, k-slot) formula for A and B, so any
    // k-permutation inside the instruction cancels in the dot product.
    int ln = lane & 15, g = lane >> 4;
    const unsigned short* brow  = &wt[wv*16 + ln][g*8];
    const unsigned short* arow0 = &tt[ln][g*8];
    const unsigned short* arow1 = &tt[16 + ln][g*8];
    f32x4 acc0 = {0.f,0.f,0.f,0.f}, acc1 = {0.f,0.f,0.f,0.f};
    #pragma unroll
    for (int kb = 0; kb < KP/32; ++kb) {
      short8 bf = *(const short8*)(brow  + kb*32);
      short8 a0 = *(const short8*)(arow0 + kb*32);
      short8 a1 = *(const short8*)(arow1 + kb*32);
      acc0 = __builtin_amdgcn_mfma_f32_16x16x32_bf16(a0, bf, acc0, 0, 0, 0);
      acc1 = __builtin_amdgcn_mfma_f32_16x16x32_bf16(a1, bf, acc1, 0, 0, 0);
    }

    // epilogue: D col = lane&15 (v), row = (lane>>4)*4 + reg (b)  [m89-verified]
    int v = vbase + wv*16 + ln;
    float ls = 0.f;
    #pragma unroll
    for (int r = 0; r < 4; ++r) {
      int b0 = g*4 + r;
      float c0 = (float)count[(size_t)b0*N_WORD + v];
      float c1 = (float)count[(size_t)(b0 + 16)*N_WORD + v];
      ls += c0 * __logf(1.f/(1.f + __expf(acc0[r])) + 1e-32f);
      ls += c1 * __logf(1.f/(1.f + __expf(acc1[r])) + 1e-32f);
    }
    #pragma unroll
    for (int off = 32; off > 0; off >>= 1) ls += __shfl_down(ls, off);
    if (lane == 0) wred[wv] = ls;
    __syncthreads();
    if (tid == 0) partials[blockIdx.x] = wred[0] + wred[1] + wred[2] + wred[3];

  } else {
    // positive terms: 8 blocks x 4 waves x 8 (b,w) pairs, f32 dots
    int pb = blockIdx.x - NGEMB;
    float ls = 0.f;
    for (int q = 0; q < 8; ++q) {
      int i = pb*32 + wv*8 + q;        // 0..255 = b*8 + w
      int b = i >> 3;
      int c = ctx[i];
      float s = 0.f;
      if (c != 1) {                     // wave-uniform branch
        float p = 0.f;
        #pragma unroll
        for (int t = 0; t < 5; ++t) {
          int d = t*64 + lane;
          if (d < DIM)
            p = fmaf(tgtN[b*DIM + d], word[(size_t)c*DIM + d], p);
        }
        #pragma unroll
        for (int off = 32; off > 0; off >>= 1) p += __shfl_down(p, off);
        s = p;                          // valid on lane 0
      }
      if (lane == 0) ls += __logf(1.f/(1.f + __expf(-s)));
    }
    if (lane == 0) wred[wv] = ls;
    __syncthreads();
    if (tid == 0) partials[blockIdx.x] = wred[0] + wred[1] + wred[2] + wred[3];
  }
}

// ---- kernel 4: deterministic final reduction in double ----
__global__ __launch_bounds__(256) void final_kernel(
    const float* __restrict__ partials, float* __restrict__ out) {
  double a = 0.0;
  for (int i = threadIdx.x; i < NBLK; i += 256) a += (double)partials[i];
  #pragma unroll
  for (int off = 32; off > 0; off >>= 1) a += __shfl_down(a, off);
  __shared__ double w2[4];
  int lane = threadIdx.x & 63, wid = threadIdx.x >> 6;
  if (lane == 0) w2[wid] = a;
  __syncthreads();
  if (threadIdx.x == 0)
    out[0] = (float)(-(w2[0] + w2[1] + w2[2] + w2[3]) / (double)BQ);
}

extern "C" void kernel_launch(void* const* d_in, const int* in_sizes, int n_in,
                              void* d_out, int out_size, void* d_ws, size_t ws_size,
                              hipStream_t stream) {
  const float* word_emb  = (const float*)d_in[0];   // [32000,300]
  const float* char_emb  = (const float*)d_in[1];   // [8000,300]
  const float* compo_emb = (const float*)d_in[2];   // [1000,300]
  const int*   chars     = (const int*)d_in[3];     // [32,4]
  const int*   compos    = (const int*)d_in[4];     // [32,8]
  const int*   ctx       = (const int*)d_in[5];     // [32,8]
  const int*   noise     = (const int*)d_in[6];     // [32,8,2392]
  float* out = (float*)d_out;

  char* ws = (char*)d_ws;
  float*          tgtN     = (float*)(ws);                  // 38400 B
  unsigned short* tgt_bf   = (unsigned short*)(ws + 38400); // 20480 B  [32][320]
  int*            count    = (int*)(ws + 58880);            // 4,096,000 B
  float*          partials = (float*)(ws + 4154880);        // NBLK floats

  prep_kernel<<<128, 256, 0, stream>>>(char_emb, compo_emb, chars, compos,
                                       tgtN, tgt_bf, count);
  hist_kernel<<<512, 256, 0, stream>>>(noise, count);
  s_loss_kernel<<<NBLK, 256, 0, stream>>>(
      (const float4*)word_emb, (const unsigned*)tgt_bf, tgtN, word_emb,
      ctx, count, partials);
  final_kernel<<<1, 256, 0, stream>>>(partials, out);
}

// Round 5
// 32.993 us; speedup vs baseline: 2.3464x; 1.5876x over previous
//
#include <hip/hip_runtime.h>

#define N_WORD 32000
#define DIM    300
#define KP     320           // K padded to 10 x 32 for MFMA
#define LROW   328           // LDS row stride in bf16 (656 B: odd*16, 2-way max)
#define BQ     32
#define WW     8
#define NNEG   2392
#define PERB   (WW*NNEG)     // 19136
#define NTOT   (BQ*PERB)     // 612352
#define VB     64            // word rows per GEMM block
#define NGEMB  (N_WORD/VB)   // 500
#define NBLK3  1024

typedef __attribute__((ext_vector_type(8))) short short8;   // 8 bf16 = 4 VGPR
typedef __attribute__((ext_vector_type(4))) float f32x4;

__device__ __forceinline__ unsigned f2b2(float lo, float hi) {
  // pack two floats to two RNE-rounded bf16 in one u32
  unsigned ul = __builtin_bit_cast(unsigned, lo);
  unsigned uh = __builtin_bit_cast(unsigned, hi);
  ul = (ul + 0x7FFF + ((ul >> 16) & 1)) >> 16;
  uh = (uh + 0x7FFF + ((uh >> 16) & 1));
  return (ul & 0xFFFFu) | (uh & 0xFFFF0000u);
}
__device__ __forceinline__ unsigned short f2b(float f) {
  unsigned u = __builtin_bit_cast(unsigned, f);
  return (unsigned short)((u + 0x7FFF + ((u >> 16) & 1)) >> 16);
}

// ---- kernel 1: tgt bags -> bf16-packed [32][320] (zero k-pad) ----
__global__ __launch_bounds__(256) void prep_kernel(
    const float* __restrict__ char_emb, const float* __restrict__ compo_emb,
    const int* __restrict__ chars, const int* __restrict__ compos,
    unsigned short* __restrict__ tgt_bf) {
  int b = blockIdx.x;
  for (int d = threadIdx.x; d < KP; d += 256) {
    float a = 0.f;
    if (d < DIM) {
      #pragma unroll
      for (int j = 0; j < 4; ++j) {
        int c = chars[b*4 + j];
        if (c != 1) a += char_emb[(size_t)c*DIM + d];
      }
      #pragma unroll
      for (int j = 0; j < 8; ++j) {
        int c = compos[b*8 + j];
        if (c != 1) a += compo_emb[(size_t)c*DIM + d];
      }
    }
    tgt_bf[b*KP + d] = (d < DIM) ? f2b(a) : (unsigned short)0;
  }
}

// ---- kernel 2: MFMA score GEMM: S[b][v] = tgt[b] . word_emb[v] ----
// 256 thr = 4 waves; block covers 64 v-rows x all 32 b, K=300 (padded 320).
// Stage: coalesced linear float4 stream of 64 contiguous word rows -> bf16 LDS.
__global__ __launch_bounds__(256) void s_gemm_kernel(
    const float4* __restrict__ w4, const unsigned* __restrict__ tgtbf2,
    float* __restrict__ S) {
  __shared__ unsigned short wt[VB][LROW];   // 41984 B
  __shared__ unsigned short tt[BQ][LROW];   // 20992 B
  int tid = threadIdx.x, wv = tid >> 6, lane = tid & 63;
  int vbase = blockIdx.x * VB;

  // stage word tile: 4800 float4, perfectly coalesced (rows contiguous)
  for (int idx = tid; idx < VB*75; idx += 256) {
    float4 x = w4[(size_t)vbase*75 + idx];
    int row = idx / 75, col = idx - row*75;
    unsigned* dst = (unsigned*)&wt[row][col*4];
    dst[0] = f2b2(x.x, x.y);
    dst[1] = f2b2(x.z, x.w);
  }
  if (tid < VB) {            // zero-pad k in [300,320)
    unsigned* dst = (unsigned*)&wt[tid][300];
    #pragma unroll
    for (int j = 0; j < 10; ++j) dst[j] = 0;
  }
  // stage tgt tile: [32][320] bf16 prepacked (incl. zero pad)
  for (int idx = tid; idx < BQ*(KP/2); idx += 256) {
    int row = idx / (KP/2), kk = idx - row*(KP/2);
    ((unsigned*)&tt[row][0])[kk] = tgtbf2[idx];
  }
  __syncthreads();

  // A and B fragments use the same lane->(row,k) formula, so any internal
  // k-permutation cancels in the dot product.
  int ln = lane & 15, g = lane >> 4;
  const unsigned short* brow  = &wt[wv*16 + ln][g*8];
  const unsigned short* arow0 = &tt[ln][g*8];
  const unsigned short* arow1 = &tt[16 + ln][g*8];
  f32x4 acc0 = {0.f,0.f,0.f,0.f}, acc1 = {0.f,0.f,0.f,0.f};
  #pragma unroll
  for (int kb = 0; kb < KP/32; ++kb) {
    short8 bf = *(const short8*)(brow  + kb*32);
    short8 a0 = *(const short8*)(arow0 + kb*32);
    short8 a1 = *(const short8*)(arow1 + kb*32);
    acc0 = __builtin_amdgcn_mfma_f32_16x16x32_bf16(a0, bf, acc0, 0, 0, 0);
    acc1 = __builtin_amdgcn_mfma_f32_16x16x32_bf16(a1, bf, acc1, 0, 0, 0);
  }

  // D: col = lane&15 (v), row = (lane>>4)*4 + reg (b)  [m89-verified]
  int v = vbase + wv*16 + ln;
  #pragma unroll
  for (int r = 0; r < 4; ++r) {
    int b0 = g*4 + r;
    S[(size_t)b0*N_WORD + v]        = acc0[r];
    S[(size_t)(b0 + 16)*N_WORD + v] = acc1[r];
  }
}

// ---- kernel 3: gather S at noise/ctx indices, sum log-sigmoid terms ----
__global__ __launch_bounds__(256) void loss_kernel(
    const float* __restrict__ S, const int* __restrict__ noise,
    const int* __restrict__ ctx, float* __restrict__ partials) {
  float a = 0.f;
  for (int i = blockIdx.x*256 + threadIdx.x; i < NTOT; i += 256*NBLK3) {
    int b = i / PERB;                 // constant divisor -> magic mul
    int idx = noise[i];
    float s = S[(size_t)b*N_WORD + idx];
    a += __logf(1.f/(1.f + __expf(s)) + 1e-32f);
  }
  if (blockIdx.x == 0) {
    int i = threadIdx.x;              // i = b*8 + w covers all 256 (b,w)
    int c = ctx[i];
    float s = (c == 1) ? 0.f : S[(size_t)(i >> 3)*N_WORD + c];
    a += __logf(1.f/(1.f + __expf(-s)));
  }
  #pragma unroll
  for (int off = 32; off > 0; off >>= 1) a += __shfl_down(a, off);
  __shared__ float wsum[4];
  int lane = threadIdx.x & 63, wid = threadIdx.x >> 6;
  if (lane == 0) wsum[wid] = a;
  __syncthreads();
  if (threadIdx.x == 0)
    partials[blockIdx.x] = wsum[0] + wsum[1] + wsum[2] + wsum[3];
}

// ---- kernel 4: deterministic final reduction in double ----
__global__ __launch_bounds__(256) void final_kernel(
    const float* __restrict__ partials, float* __restrict__ out) {
  double a = 0.0;
  for (int i = threadIdx.x; i < NBLK3; i += 256) a += (double)partials[i];
  #pragma unroll
  for (int off = 32; off > 0; off >>= 1) a += __shfl_down(a, off);
  __shared__ double w2[4];
  int lane = threadIdx.x & 63, wid = threadIdx.x >> 6;
  if (lane == 0) w2[wid] = a;
  __syncthreads();
  if (threadIdx.x == 0)
    out[0] = (float)(-(w2[0] + w2[1] + w2[2] + w2[3]) / (double)BQ);
}

extern "C" void kernel_launch(void* const* d_in, const int* in_sizes, int n_in,
                              void* d_out, int out_size, void* d_ws, size_t ws_size,
                              hipStream_t stream) {
  const float* word_emb  = (const float*)d_in[0];   // [32000,300]
  const float* char_emb  = (const float*)d_in[1];   // [8000,300]
  const float* compo_emb = (const float*)d_in[2];   // [1000,300]
  const int*   chars     = (const int*)d_in[3];     // [32,4]
  const int*   compos    = (const int*)d_in[4];     // [32,8]
  const int*   ctx       = (const int*)d_in[5];     // [32,8]
  const int*   noise     = (const int*)d_in[6];     // [32,8,2392]
  float* out = (float*)d_out;

  char* ws = (char*)d_ws;
  unsigned short* tgt_bf   = (unsigned short*)(ws);         // 20480 B [32][320]
  float*          S        = (float*)(ws + 20480);          // 4,096,000 B
  float*          partials = (float*)(ws + 20480 + 4096000);// NBLK3 floats

  prep_kernel<<<BQ, 256, 0, stream>>>(char_emb, compo_emb, chars, compos, tgt_bf);
  s_gemm_kernel<<<NGEMB, 256, 0, stream>>>(
      (const float4*)word_emb, (const unsigned*)tgt_bf, S);
  loss_kernel<<<NBLK3, 256, 0, stream>>>(S, noise, ctx, partials);
  final_kernel<<<1, 256, 0, stream>>>(partials, out);
}